// Round 4
// baseline (261.894 us; speedup 1.0000x reference)
//
#include <hip/hip_runtime.h>

// MEASUREMENT PROBE (Round 4). Real work identical to R3. Adds 4 dummy
// sequential weight streams (shifted mod nW-8192) folded through an
// asm-opaque zero, multiplying kernel HBM fetch ~5x (~640 MB) so the kernel
// exceeds the 78-us poison-fills and becomes visible in rocprof top-5 with
// its own FETCH_SIZE / dur / VALUBusy. Purpose: measure the achievable BW of
// this access pattern. Kernel time decomposition so far is inferential:
// total 196-201 us = ~130-175 us fixed harness traffic (537 MB d_ws fill @78,
// 134 MB w-restore @~45, gaps) + kernel in [21, 65]. This probe pins it.

constexpr int N = 8192;      // N_IN == N_OUT
constexpr int BATCH = 8;
constexpr int ROWS = 4;
constexpr int THREADS = 256;
constexpr int VEC = 4;
constexpr int TILE = THREADS * VEC;   // 1024 columns per block-iteration
constexpr long long NW = 33591286LL;  // packed weight count
constexpr long long MODW = NW - 8192; // extra-stream bases stay in-bounds
constexpr int XTRA = 4;               // dummy streams (probe only)

typedef float f32x4v __attribute__((ext_vector_type(4)));
typedef f32x4v __attribute__((aligned(4))) f32x4u;

__global__ __launch_bounds__(THREADS, 4)
void tri_linear_kernel(const float* __restrict__ x,
                       const float* __restrict__ w,
                       const float* __restrict__ bias,
                       float* __restrict__ out) {
  const int t = threadIdx.x;
  const int r0 = blockIdx.x * ROWS;

  int c0[ROWS];
  const float* wrow[ROWS];
  const float* wrowx[XTRA][ROWS];     // dummy streams; block-uniform -> SGPRs
#pragma unroll
  for (int i = 0; i < ROWS; ++i) {
    const int r = r0 + i;
    c0[i] = (r > 4) ? (r - 4) : 0;
    // off(r) = 8192*r - (r-5)(r-4)/2 for r>=5 (off(8192) == NW)
    long long off = (r <= 5)
        ? (long long)r * N
        : (long long)r * N - ((long long)(r - 5) * (long long)(r - 4)) / 2;
    wrow[i] = w + (off - (long long)c0[i]);
#pragma unroll
    for (int p = 0; p < XTRA; ++p) {
      long long offp = (off + (long long)(p + 1) * 6719059LL) % MODW;
      wrowx[p][i] = w + (offp - (long long)c0[i]);  // reads stay < NW
    }
  }
  const int cbA = c0[0] & ~(TILE - 1);

  float acc[ROWS][BATCH];
#pragma unroll
  for (int i = 0; i < ROWS; ++i)
#pragma unroll
    for (int b = 0; b < BATCH; ++b) acc[i][b] = 0.0f;

  // ---- Edge tile (real work only, predicated on triangular boundary) ----
  {
    const int c = cbA + VEC * t;
    float4 xv[BATCH];
#pragma unroll
    for (int b = 0; b < BATCH; ++b)
      xv[b] = *(const float4*)(x + b * N + c);
#pragma unroll
    for (int i = 0; i < ROWS; ++i) {
#pragma unroll
      for (int j = 0; j < VEC; ++j) {
        const int cj = c + j;
        const float wv = (cj >= c0[i]) ? wrow[i][cj] : 0.0f;
#pragma unroll
        for (int b = 0; b < BATCH; ++b) {
          const float* xe = reinterpret_cast<const float*>(&xv[b]);
          acc[i][b] = fmaf(wv, xe[j], acc[i][b]);
        }
      }
    }
  }

  // ---- Main loop: real pass + 4 dummy streams (probe) ----
  f32x4v dummy4 = {0.f, 0.f, 0.f, 0.f};
  for (int cb = cbA + TILE; cb < N; cb += TILE) {
    const int c = cb + VEC * t;
    f32x4v wv[ROWS];
#pragma unroll
    for (int i = 0; i < ROWS; ++i)
      wv[i] = *(const f32x4u*)(wrow[i] + c);
    float4 xv[BATCH];
#pragma unroll
    for (int b = 0; b < BATCH; ++b)
      xv[b] = *(const float4*)(x + b * N + c);
#pragma unroll
    for (int i = 0; i < ROWS; ++i)
#pragma unroll
      for (int j = 0; j < VEC; ++j)
#pragma unroll
        for (int b = 0; b < BATCH; ++b) {
          const float* xe = reinterpret_cast<const float*>(&xv[b]);
          acc[i][b] = fmaf(wv[i][j], xe[j], acc[i][b]);
        }
    // Dummy streams: same pattern, disjoint regions -> ~4x extra HBM fetch.
#pragma unroll
    for (int p = 0; p < XTRA; ++p)
#pragma unroll
      for (int i = 0; i < ROWS; ++i)
        dummy4 += *(const f32x4u*)(wrowx[p][i] + c);
  }

  // Fold dummy through an opaque zero (not DCE-able, numerically exact 0 add).
  float zk;
  asm volatile("v_mov_b32 %0, 0" : "=v"(zk));
  acc[0][0] = fmaf(dummy4.x + dummy4.y + dummy4.z + dummy4.w, zk, acc[0][0]);

  // ---- Reduction (unchanged): 34 KB LDS, 4 blocks/CU ----
  __shared__ float red[THREADS][ROWS * BATCH + 1];
#pragma unroll
  for (int i = 0; i < ROWS; ++i)
#pragma unroll
    for (int b = 0; b < BATCH; ++b)
      red[t][i * BATCH + b] = acc[i][b];
  __syncthreads();

  const int s = t & 31;
  const int part = t >> 5;
  float p = 0.0f;
#pragma unroll
  for (int k = 0; k < 32; ++k) p += red[part * 32 + k][s];

  __shared__ float red2[32][9];
  red2[s][part] = p;
  __syncthreads();

  if (t < 32) {
    float total = 0.0f;
#pragma unroll
    for (int g = 0; g < 8; ++g) total += red2[t][g];
    const int i = t >> 3, b = t & 7;
    const int r = r0 + i;
    out[b * N + (N - 1 - r)] = total + bias[r];
  }
}

extern "C" void kernel_launch(void* const* d_in, const int* in_sizes, int n_in,
                              void* d_out, int out_size, void* d_ws, size_t ws_size,
                              hipStream_t stream) {
  const float* x    = (const float*)d_in[0];  // [8, 8192]
  const float* w    = (const float*)d_in[1];  // [33591286] packed triangular
  const float* bias = (const float*)d_in[2];  // [8192]
  float* out = (float*)d_out;                 // [8, 8192]
  tri_linear_kernel<<<N / ROWS, THREADS, 0, stream>>>(x, w, bias, out);
}